// Round 12
// baseline (107.057 us; speedup 1.0000x reference)
//
#include <hip/hip_runtime.h>

// CurvatureLoss: B=4, N=4096, fp32.
// R12: five structurally different scalar kernels all land 43-50us -> the
// invariant is ~20M VALU wave-inst @ ~0.78/cyc/CU. Only removing keygen
// FMAs changes the count => MFMA keygen:
//  - key = q.c - 0.5|c|^2 as mfma_f32_16x16x32_bf16 with hi/lo bf16 split
//    packed along K: A row k0-15 = [qh(4),ql(4)]x2 (quads 0,1; 2,3 zero),
//    B col quad0 = [ch,ch], quad1 = [cl,cl] -> D = (qh+ql).(ch+cl), fp32
//    accumulate. Key err ~3e-5 << NN gaps ~1e-3.
//  - 3 MFMAs/tile (oo, ao, aa) = 768 keys per ~48 VALU inst (selection
//    stays on VALU: 12 embed5 + 28 med3/max trackers).
//  - wave = 16-query tile x 512-candidate split (32 tiles); block = 4 waves,
//    2048 blocks = 8192 waves. LDS: 16.4KB staged bf16 cands + zero block,
//    reused as 24KB merge scratch.
//  - C layout col=lane&15,row=(lane>>4)*4+reg [m89-verified]; A layout
//    A[m=lane&15][k=quad*8+j] [m120]; B assumed mirror (n=lane&15).
// merge_epilogue = R11 field-major, NCB=8.

typedef __attribute__((ext_vector_type(8))) short bf16x8;
typedef __attribute__((ext_vector_type(4))) float f32x4;
typedef __attribute__((ext_vector_type(4))) int   i32x4;

constexpr int BB   = 4;
constexpr int NN   = 4096;
constexpr int NQ   = BB * NN;        // 16384
constexpr int NSPL = 8;              // candidate splits per batch
constexpr int SPL  = NN / NSPL;      // 512 candidates per split
constexpr int NTIL = SPL / 16;       // 32 16-cand tiles per split
constexpr int NCB  = NSPL;           // partial chunks per query
constexpr int NBLK = (NQ / 64) * NSPL;  // 2048 blocks (4 query-tiles each)
constexpr float NEGBIG = -3.402823466e+38f;

__device__ __forceinline__ float fmed3(float a, float b, float c) {
    return __builtin_amdgcn_fmed3f(a, b, c);
}
__device__ __forceinline__ float embed5(float t, unsigned eb) {
    return __uint_as_float((__float_as_uint(t) & 0xFFFFFFE0u) | eb);
}
__device__ __forceinline__ unsigned short bf16_rne(float x) {
    unsigned u = __float_as_uint(x);
    unsigned r = u + 0x7FFFu + ((u >> 16) & 1u);
    return (unsigned short)(r >> 16);
}
__device__ __forceinline__ float bf16_f32(unsigned short h) {
    return __uint_as_float(((unsigned)h) << 16);
}
__device__ __forceinline__ bf16x8 as_bf16x8(i32x4 v) {
    union { i32x4 i; bf16x8 s; } u; u.i = v; return u.s;
}

__global__ __launch_bounds__(256, 6) void knn_mfma(
    const float* __restrict__ ori, const float* __restrict__ adv,
    float* __restrict__ partial)
{
    const int tid   = threadIdx.x;
    const int lane  = tid & 63;
    const int w     = tid >> 6;          // wave 0..3
    const int col   = lane & 15;         // candidate col / A query row
    const int quad  = lane >> 4;         // 0..3
    const int qb4   = blockIdx.x >> 3;   // 0..255 (64-query groups)
    const int split = blockIdx.x & 7;    // candidate split
    const int Q0g   = qb4 * 64 + w * 16; // global query base of this wave
    const int b     = Q0g >> 12;         // batch
    const int Qb0   = Q0g & (NN - 1);    // batch-local query base
    const int S0    = split * SPL;       // batch-local candidate base

    // LDS: [0,8192) ori cands (16B: hi8|lo8), [8192,16384) adv cands,
    // [16384,16400) zero block. Reused post-loop as 24KB merge scratch.
    __shared__ __align__(16) char lds[24576];

    // ---- stage 512 candidates as hi/lo bf16 (w = -0.5|c|^2) ----
    {
        if (tid < 4) ((unsigned*)(lds + 16384))[tid] = 0u;
        #pragma unroll
        for (int s = 0; s < 2; ++s) {
            const int jj = tid + s * 256;               // 0..511
            const size_t cg = (size_t)b * NN + S0 + jj; // global candidate
            #pragma unroll
            for (int role = 0; role < 2; ++role) {
                const float* p = (role ? adv : ori) + cg * 3;
                const float x = p[0], y = p[1], z = p[2];
                const float wc = -0.5f * (x * x + y * y + z * z);
                float v[4] = {x, y, z, wc};
                unsigned short h[4], l[4];
                #pragma unroll
                for (int i = 0; i < 4; ++i) {
                    h[i] = bf16_rne(v[i]);
                    l[i] = bf16_rne(v[i] - bf16_f32(h[i]));
                }
                unsigned* dst = (unsigned*)(lds + role * 8192 + jj * 16);
                dst[0] = (unsigned)h[0] | ((unsigned)h[1] << 16);
                dst[1] = (unsigned)h[2] | ((unsigned)h[3] << 16);
                dst[2] = (unsigned)l[0] | ((unsigned)l[1] << 16);
                dst[3] = (unsigned)l[2] | ((unsigned)l[3] << 16);
            }
        }
    }

    // ---- A fragments (this wave's 16 queries, ori-role and adv-role) ----
    // lane supplies A[m=col][k=quad*8+j]; quads 0,1: [qh(4),ql(4)]; 2,3: 0.
    bf16x8 A_ori, A_adv;
    {
        const size_t qg = (size_t)Q0g + col;   // global query for A data
        const bool live = (quad < 2);
        #pragma unroll
        for (int role = 0; role < 2; ++role) {
            const float* p = (role ? adv : ori) + qg * 3;
            const float x = p[0], y = p[1], z = p[2];
            float v[4] = {x, y, z, 1.0f};
            unsigned short h[4], l[4];
            #pragma unroll
            for (int i = 0; i < 4; ++i) {
                h[i] = bf16_rne(v[i]);
                l[i] = bf16_rne(v[i] - bf16_f32(h[i]));
            }
            bf16x8 f;
            f[0] = (short)h[0]; f[1] = (short)h[1];
            f[2] = (short)h[2]; f[3] = (short)h[3];
            f[4] = (short)l[0]; f[5] = (short)l[1];
            f[6] = (short)l[2]; f[7] = (short)l[3];
            #pragma unroll
            for (int i = 0; i < 8; ++i) f[i] = live ? f[i] : (short)0;
            if (role) A_adv = f; else A_ori = f;
        }
    }
    __syncthreads();

    // per-lane B addressing: quads 0,1 walk the staged candidates
    // (hi for quad0, lo for quad1); quads 2,3 pin to the zero block.
    const bool  bl   = (quad < 2);
    const int   step = bl ? 256 : 0;                    // bytes per tile
    int off_o = bl ? (col * 16 + (quad & 1) * 8) : 16384;
    // adv area is +8192 for live lanes, same zero block otherwise
    const int adv_d = bl ? 8192 : 0;

    // trackers: top-3 oo/aa (self guaranteed rank-1 when present), max ao
    float oo0[4], oo1[4], oo2[4], aa0[4], aa1[4], aa2[4], ao[4];
    #pragma unroll
    for (int r = 0; r < 4; ++r) {
        oo0[r] = oo1[r] = oo2[r] = NEGBIG;
        aa0[r] = aa1[r] = aa2[r] = NEGBIG;
        ao[r] = NEGBIG;
    }

    const f32x4 zc = {0.0f, 0.0f, 0.0f, 0.0f};

    #pragma unroll 4
    for (int t = 0; t < NTIL; ++t) {
        const uint2 dor = *(const uint2*)(lds + off_o);
        const uint2 dad = *(const uint2*)(lds + off_o + adv_d);
        off_o += step;
        const bf16x8 B_ori = as_bf16x8((i32x4){(int)dor.x, (int)dor.y,
                                               (int)dor.x, (int)dor.y});
        const bf16x8 B_adv = as_bf16x8((i32x4){(int)dad.x, (int)dad.y,
                                               (int)dad.x, (int)dad.y});

        const f32x4 Coo = __builtin_amdgcn_mfma_f32_16x16x32_bf16(A_ori, B_ori, zc, 0, 0, 0);
        const f32x4 Cao = __builtin_amdgcn_mfma_f32_16x16x32_bf16(A_adv, B_ori, zc, 0, 0, 0);
        const f32x4 Caa = __builtin_amdgcn_mfma_f32_16x16x32_bf16(A_adv, B_adv, zc, 0, 0, 0);

        const unsigned eb = (unsigned)(NTIL - 1 - t);   // smaller t -> larger key
        #pragma unroll
        for (int r = 0; r < 4; ++r) {
            const float koo = embed5(Coo[r], eb);
            oo2[r] = fmed3(oo1[r], oo2[r], koo);
            oo1[r] = fmed3(oo0[r], oo1[r], koo);
            oo0[r] = fmaxf(oo0[r], koo);
            const float kaa = embed5(Caa[r], eb);
            aa2[r] = fmed3(aa1[r], aa2[r], kaa);
            aa1[r] = fmed3(aa0[r], aa1[r], kaa);
            aa0[r] = fmaxf(aa0[r], kaa);
            ao[r] = fmaxf(ao[r], embed5(Cao[r], eb));
        }
    }

    // self-collapse: wave covers its own queries iff Qb0's 512-block == split.
    // self key C[row][col] has col == row (= quad*4+r), guaranteed rank-1.
    const bool covers = ((Qb0 >> 9) == split);
    #pragma unroll
    for (int r = 0; r < 4; ++r) {
        const bool s = covers && (col == quad * 4 + r);
        oo0[r] = s ? oo1[r] : oo0[r];  oo1[r] = s ? oo2[r] : oo1[r];
        aa0[r] = s ? aa1[r] : aa0[r];  aa1[r] = s ? aa2[r] : aa1[r];
    }

    __syncthreads();   // staged tile dead; reuse LDS as merge scratch
    // scratch slot (w, row, col) = 6 floats: oo0,oo1,aa0,aa1,ao,(pad)
    {
        float* scr = (float*)lds;
        #pragma unroll
        for (int r = 0; r < 4; ++r) {
            const int row = quad * 4 + r;
            float* s = scr + ((w * 16 + row) * 16 + col) * 6;
            s[0] = oo0[r]; s[1] = oo1[r];
            s[2] = aa0[r]; s[3] = aa1[r];
            s[4] = ao[r];
        }
    }
    __syncthreads();

    if (tid < 64) {
        // merge query (w2, row) across 16 cols; ascending col + strict >
        // keeps smaller j on ties (j = S0 + (31-embed)*16 + col).
        const int w2 = tid >> 4, row = tid & 15;
        const float* scr = (const float*)lds;
        float ko0 = NEGBIG, ko1 = NEGBIG, ka0 = NEGBIG, ka1 = NEGBIG, km = NEGBIG;
        int co0 = 0, co1 = 0, ca0 = 0, ca1 = 0, cm = 0;
        #pragma unroll
        for (int c = 0; c < 16; ++c) {
            const float* s = scr + ((w2 * 16 + row) * 16 + c) * 6;
            float v0, v1;
            v0 = s[0]; v1 = s[1];
            if (v0 > ko0)      { ko1 = ko0; co1 = co0; ko0 = v0; co0 = c; }
            else if (v0 > ko1) { ko1 = v0; co1 = c; }
            if (v1 > ko1)      { ko1 = v1; co1 = c; }
            v0 = s[2]; v1 = s[3];
            if (v0 > ka0)      { ka1 = ka0; ca1 = ca0; ka0 = v0; ca0 = c; }
            else if (v0 > ka1) { ka1 = v0; ca1 = c; }
            if (v1 > ka1)      { ka1 = v1; ca1 = c; }
            if (s[4] > km)     { km = s[4]; cm = c; }
        }
        const int jo0 = S0 + (NTIL - 1 - (int)(__float_as_uint(ko0) & 31u)) * 16 + co0;
        const int jo1 = S0 + (NTIL - 1 - (int)(__float_as_uint(ko1) & 31u)) * 16 + co1;
        const int ja0 = S0 + (NTIL - 1 - (int)(__float_as_uint(ka0) & 31u)) * 16 + ca0;
        const int ja1 = S0 + (NTIL - 1 - (int)(__float_as_uint(ka1) & 31u)) * 16 + ca1;
        const int jm  = S0 + (NTIL - 1 - (int)(__float_as_uint(km)  & 31u)) * 16 + cm;

        const int q = qb4 * 64 + w2 * 16 + row;   // global query id
        float vals[10];
        vals[0] = ko0; vals[1] = ko1; vals[2] = ka0; vals[3] = ka1; vals[4] = km;
        vals[5] = __int_as_float(jo0); vals[6] = __int_as_float(jo1);
        vals[7] = __int_as_float(ja0); vals[8] = __int_as_float(ja1);
        vals[9] = __int_as_float(jm);
        #pragma unroll
        for (int f = 0; f < 10; ++f)
            partial[((size_t)f * NCB + split) * NQ + q] = vals[f];
    }
}

__device__ __forceinline__ float uad(const float* __restrict__ pts, int j,
                                     float px, float py, float pz,
                                     float nx, float ny, float nz) {
    const float* p = pts + (size_t)j * 3;
    const float vx = p[0] - px, vy = p[1] - py, vz = p[2] - pz;
    const float s  = vx * vx + vy * vy + vz * vz + 1e-12f;
    return fabsf((vx * nx + vy * ny + vz * nz) * (1.0f / sqrtf(s)));
}

__global__ __launch_bounds__(256) void merge_epilogue(
    const float* __restrict__ partial, const float* __restrict__ ori,
    const float* __restrict__ adv, const float* __restrict__ nrm,
    float* __restrict__ out)
{
    const int q  = blockIdx.x * 256 + threadIdx.x;   // 0..16383
    const int b  = q >> 12;
    const int qb = q & (NN - 1);

    float ko0 = NEGBIG, ko1 = NEGBIG, ka0 = NEGBIG, ka1 = NEGBIG, km = NEGBIG;
    int jo0 = 0, jo1 = 0, ja0 = 0, ja1 = 0, jm = 0;
    #pragma unroll
    for (int cb = 0; cb < NCB; ++cb) {
        const float c0 = partial[((size_t)0 * NCB + cb) * NQ + q];
        const float c1 = partial[((size_t)1 * NCB + cb) * NQ + q];
        const float d0 = partial[((size_t)2 * NCB + cb) * NQ + q];
        const float d1 = partial[((size_t)3 * NCB + cb) * NQ + q];
        const float mk = partial[((size_t)4 * NCB + cb) * NQ + q];
        const int   i0 = __float_as_int(partial[((size_t)5 * NCB + cb) * NQ + q]);
        const int   i1 = __float_as_int(partial[((size_t)6 * NCB + cb) * NQ + q]);
        const int   i2 = __float_as_int(partial[((size_t)7 * NCB + cb) * NQ + q]);
        const int   i3 = __float_as_int(partial[((size_t)8 * NCB + cb) * NQ + q]);
        const int   i4 = __float_as_int(partial[((size_t)9 * NCB + cb) * NQ + q]);

        if (c0 > ko0)      { ko1 = ko0; jo1 = jo0; ko0 = c0; jo0 = i0; }
        else if (c0 > ko1) { ko1 = c0; jo1 = i0; }
        if (c1 > ko1)      { ko1 = c1; jo1 = i1; }
        if (d0 > ka0)      { ka1 = ka0; ja1 = ja0; ka0 = d0; ja0 = i2; }
        else if (d0 > ka1) { ka1 = d0; ja1 = i2; }
        if (d1 > ka1)      { ka1 = d1; ja1 = i3; }
        if (mk > km)       { km = mk; jm = i4; }
    }

    const float* ob = ori + (size_t)b * NN * 3;
    const float* ab = adv + (size_t)b * NN * 3;
    const float* nb = nrm + (size_t)b * NN * 3;

    const float qox = ob[3 * qb], qoy = ob[3 * qb + 1], qoz = ob[3 * qb + 2];
    const float qax = ab[3 * qb], qay = ab[3 * qb + 1], qaz = ab[3 * qb + 2];
    const float nx = nb[3 * qb], ny = nb[3 * qb + 1], nz = nb[3 * qb + 2];
    const float ok = 0.5f * (uad(ob, jo0, qox, qoy, qoz, nx, ny, nz) +
                             uad(ob, jo1, qox, qoy, qoz, nx, ny, nz));
    const float ax = nb[3 * jm], ay = nb[3 * jm + 1], az = nb[3 * jm + 2];
    const float ak = 0.5f * (uad(ab, ja0, qax, qay, qaz, ax, ay, az) +
                             uad(ab, ja1, qax, qay, qaz, ax, ay, az));
    const float d = ak - ok;
    float val = d * d;

    #pragma unroll
    for (int off = 32; off > 0; off >>= 1) val += __shfl_down(val, off);
    __shared__ float ls[4];
    if ((threadIdx.x & 63) == 0) ls[threadIdx.x >> 6] = val;
    __syncthreads();
    if (threadIdx.x == 0)
        atomicAdd(out, (ls[0] + ls[1] + ls[2] + ls[3]) * (1.0f / (float)(BB * NN)));
}

extern "C" void kernel_launch(void* const* d_in, const int* in_sizes, int n_in,
                              void* d_out, int out_size, void* d_ws, size_t ws_size,
                              hipStream_t stream) {
    const float* ori = (const float*)d_in[0];
    const float* adv = (const float*)d_in[1];
    const float* nrm = (const float*)d_in[2];
    float* out = (float*)d_out;

    float* part = (float*)d_ws;   // 10 fields x 8 cb x 16384 x 4 B = 5.24 MB
                                  // (ws >= 10.49 MB proven by R10/R11 runs)

    hipMemsetAsync(out, 0, sizeof(float), stream);
    hipLaunchKernelGGL(knn_mfma, dim3(NBLK), dim3(256), 0, stream,
                       ori, adv, part);
    hipLaunchKernelGGL(merge_epilogue, dim3(NQ / 256), dim3(256), 0, stream,
                       part, ori, adv, nrm, out);
}